// Round 7
// baseline (162.147 us; speedup 1.0000x reference)
//
#include <hip/hip_runtime.h>
#include <hip/hip_bf16.h>

#define NROWS 131072
#define DK    1024
#define CCLS  21
#define CTF   84
#define NCOL  105          // 21 + 84
#define NCT   7            // 112 padded cols / 16
#define BM    128          // 4 waves x 32 rows
#define BKF   64           // f32 per slab (256 B per row per slab)
#define NSLAB (DK / BKF)   // 16

typedef __attribute__((ext_vector_type(4))) float f32x4;
typedef __attribute__((ext_vector_type(8))) short bf16x8;

typedef const __attribute__((address_space(1))) void GV;
typedef __attribute__((address_space(3))) void LV;

__device__ __forceinline__ unsigned short f2bf_rne(float x) {
    union { float f; unsigned u; } v; v.f = x;
    unsigned r = v.u + 0x7fffu + ((v.u >> 16) & 1u);
    return (unsigned short)(r >> 16);
}

__device__ __forceinline__ unsigned pack2(float lo, float hi) {
    union { float f; unsigned u; } a, b; a.f = lo; b.f = hi;
    return ((a.u + 0x8000u) >> 16) | ((b.u + 0x8000u) & 0xffff0000u);
}

__device__ __forceinline__ bf16x8 cvt8v(const f32x4 lo, const f32x4 hi) {
    union { unsigned u[4]; bf16x8 v; } r;
    r.u[0] = pack2(lo[0], lo[1]);
    r.u[1] = pack2(lo[2], lo[3]);
    r.u[2] = pack2(hi[0], hi[1]);
    r.u[3] = pack2(hi[2], hi[3]);
    return r.v;
}

// Pack [W_cls | W_tf | zero-pad] into bf16 MFMA B-fragment order (verified):
// element ((kt*NCT+ct)*64+lane)*8 + j = B[k][col],
// col = ct*16 + (lane&15), k = kt*32 + (lane>>4)*8 + j
__global__ void pack_B_kernel(const float* __restrict__ Wc,
                              const float* __restrict__ Wt,
                              unsigned short* __restrict__ Bp) {
    const int frag = blockIdx.x;           // 224 total
    const int kt = frag / NCT, ct = frag % NCT;
    const int lane = threadIdx.x;          // 64
    const int col = ct * 16 + (lane & 15);
    const int k0  = kt * 32 + ((lane >> 4) << 3);
    bf16x8 o;
#pragma unroll
    for (int j = 0; j < 8; ++j) {
        const int k = k0 + j;
        float v = 0.0f;
        if (col < CCLS)      v = Wc[k * CCLS + col];
        else if (col < NCOL) v = Wt[k * CTF + (col - CCLS)];
        o[j] = (short)f2bf_rne(v);
    }
    *reinterpret_cast<bf16x8*>(Bp + ((size_t)frag * 64 + lane) * 8) = o;
}

// R4 structure (measured best, 153us) + cache-policy deltas:
//   - A-stream DMA marked non-temporal (aux=2 / CPol NT): A has zero reuse;
//     evict-first keeps it from churning L2/L3 and evicting the hot B buffer.
//   - epilogue stores non-temporal (output never re-read).
// Everything else identical to round 4.
__global__ __launch_bounds__(256, 2)
void roi_gemm_kernel(const float* __restrict__ F,
                     const unsigned short* __restrict__ Bp,
                     const float* __restrict__ bcls,
                     const float* __restrict__ btf,
                     float* __restrict__ out) {
    // [buf][wave][row 0..31][chunk16B 0..15] = 64 KiB
    __shared__ float Alds[2][4][32][BKF];

    const int t    = threadIdx.x;
    const int wave = t >> 6;
    const int lane = t & 63;
    const int fr   = lane & 15;      // A/C row-in-tile, B col
    const int fq   = lane >> 4;      // 0..3
    const int sw   = fr & 7;         // read-side XOR swizzle

    const long rw = (long)blockIdx.x * BM + wave * 32;

    // staging sources: DMA instr q writes rows q*4..q*4+3 linearly; lane's
    // row r = q*4+fq, slot fr must hold global chunk fr ^ (r&7).
    // r&7 = fq (q even) or fq+4 (q odd).
    const float* srcE = F + (size_t)(rw + fq) * DK + ((fr ^ fq) << 2);
    const float* srcO = F + (size_t)(rw + fq) * DK + ((fr ^ (fq + 4)) << 2);
    const unsigned short* bb = Bp + (size_t)lane * 8;

    f32x4 acc[2][NCT];
#pragma unroll
    for (int a = 0; a < 2; ++a)
#pragma unroll
        for (int b = 0; b < NCT; ++b)
            acc[a][b] = (f32x4){0.f, 0.f, 0.f, 0.f};

#define STAGE(BUF, S) do {                                                   \
    const float* _e = srcE + (size_t)(S) * BKF;                              \
    const float* _o = srcO + (size_t)(S) * BKF;                              \
    _Pragma("unroll")                                                        \
    for (int q = 0; q < 8; ++q) {                                            \
        const float* g = ((q & 1) ? _o : _e) + (size_t)q * 4 * DK;           \
        __builtin_amdgcn_global_load_lds((GV*)g,                             \
            (LV*)&Alds[BUF][wave][q * 4][0], 16, 0, 2 /* CPol NT */);        \
    }                                                                        \
} while (0)

    STAGE(0, 0);   // prologue: 8 DMA outstanding

    for (int s = 0; s < NSLAB; ++s) {
        const int buf = s & 1;

        __builtin_amdgcn_sched_barrier(0);
        // B fragments for this slab (L2-resident), 14 loads, default policy
        bf16x8 bf[2][NCT];
#pragma unroll
        for (int kt = 0; kt < 2; ++kt)
#pragma unroll
            for (int ct = 0; ct < NCT; ++ct)
                bf[kt][ct] = *reinterpret_cast<const bf16x8*>(
                    bb + ((size_t)((s * 2 + kt) * NCT + ct) * 512));
        __builtin_amdgcn_sched_barrier(0);

        // FIFO: [DMA(s)=8][B(s)=14][DMA(s+1)=8] -> vmcnt(8) completes
        // DMA(s)+B(s) while keeping DMA(s+1) in flight.
        if (s + 1 < NSLAB) {
            STAGE((s + 1) & 1, s + 1);
            __builtin_amdgcn_sched_barrier(0);
            asm volatile("s_waitcnt vmcnt(8)" ::: "memory");
        } else {
            asm volatile("s_waitcnt vmcnt(0)" ::: "memory");
        }
        __builtin_amdgcn_sched_barrier(0);

#pragma unroll
        for (int kt = 0; kt < 2; ++kt) {
            bf16x8 af[2];
#pragma unroll
            for (int rt = 0; rt < 2; ++rt) {
                const float* lpr = &Alds[buf][wave][rt * 16 + fr][0];
                const int c0 = kt * 8 + fq * 2;
                const f32x4 lo = *reinterpret_cast<const f32x4*>(
                    lpr + (((c0 + 0) ^ sw) << 2));
                const f32x4 hi = *reinterpret_cast<const f32x4*>(
                    lpr + (((c0 + 1) ^ sw) << 2));
                af[rt] = cvt8v(lo, hi);
            }
#pragma unroll
            for (int ct = 0; ct < NCT; ++ct) {
                acc[0][ct] = __builtin_amdgcn_mfma_f32_16x16x32_bf16(
                    af[0], bf[kt][ct], acc[0][ct], 0, 0, 0);
                acc[1][ct] = __builtin_amdgcn_mfma_f32_16x16x32_bf16(
                    af[1], bf[kt][ct], acc[1][ct], 0, 0, 0);
            }
        }
    }
#undef STAGE

    // epilogue: bias + scatter into the two outputs (layout verified);
    // non-temporal stores (output never re-read by this kernel)
    float* out_tf = out + (size_t)NROWS * CCLS;
#pragma unroll
    for (int rt = 0; rt < 2; ++rt) {
        const long rbase = rw + rt * 16 + (fq << 2);
#pragma unroll
        for (int ct = 0; ct < NCT; ++ct) {
            const int col = ct * 16 + fr;
            if (col >= NCOL) continue;
            const float bias = (col < CCLS) ? bcls[col] : btf[col - CCLS];
#pragma unroll
            for (int j = 0; j < 4; ++j) {
                const long row = rbase + j;
                const float v = acc[rt][ct][j] + bias;
                if (col < CCLS)
                    __builtin_nontemporal_store(v, &out[row * CCLS + col]);
                else
                    __builtin_nontemporal_store(v, &out_tf[row * CTF + (col - CCLS)]);
            }
        }
    }
}

extern "C" void kernel_launch(void* const* d_in, const int* in_sizes, int n_in,
                              void* d_out, int out_size, void* d_ws, size_t ws_size,
                              hipStream_t stream) {
    const float* F  = (const float*)d_in[0];
    const float* Wc = (const float*)d_in[1];
    const float* bc = (const float*)d_in[2];
    const float* Wt = (const float*)d_in[3];
    const float* bt = (const float*)d_in[4];
    unsigned short* Bp = (unsigned short*)d_ws;   // 229,376 B

    pack_B_kernel<<<NCT * (DK / 32), 64, 0, stream>>>(Wc, Wt, Bp);
    roi_gemm_kernel<<<NROWS / BM, 256, 0, stream>>>(F, Bp, bc, bt,
                                                    (float*)d_out);
}

// Round 8
// 153.111 us; speedup vs baseline: 1.0590x; 1.0590x over previous
//
#include <hip/hip_runtime.h>
#include <hip/hip_bf16.h>

#define NROWS 131072
#define DK    1024
#define CCLS  21
#define CTF   84
#define NCOL  105          // 21 + 84
#define NCT   7            // 112 padded cols / 16
#define BM    128          // 4 waves x 32 rows
#define BKF   64           // f32 per slab (256 B per row per slab)
#define NSLAB (DK / BKF)   // 16

typedef __attribute__((ext_vector_type(4))) float f32x4;
typedef __attribute__((ext_vector_type(8))) short bf16x8;

typedef const __attribute__((address_space(1))) void GV;
typedef __attribute__((address_space(3))) void LV;

__device__ __forceinline__ unsigned short f2bf_rne(float x) {
    union { float f; unsigned u; } v; v.f = x;
    unsigned r = v.u + 0x7fffu + ((v.u >> 16) & 1u);
    return (unsigned short)(r >> 16);
}

__device__ __forceinline__ unsigned pack2(float lo, float hi) {
    union { float f; unsigned u; } a, b; a.f = lo; b.f = hi;
    return ((a.u + 0x8000u) >> 16) | ((b.u + 0x8000u) & 0xffff0000u);
}

__device__ __forceinline__ bf16x8 cvt8v(const f32x4 lo, const f32x4 hi) {
    union { unsigned u[4]; bf16x8 v; } r;
    r.u[0] = pack2(lo[0], lo[1]);
    r.u[1] = pack2(lo[2], lo[3]);
    r.u[2] = pack2(hi[0], hi[1]);
    r.u[3] = pack2(hi[2], hi[3]);
    return r.v;
}

// Pack [W_cls | W_tf | zero-pad] into bf16 MFMA B-fragment order (verified):
// element ((kt*NCT+ct)*64+lane)*8 + j = B[k][col],
// col = ct*16 + (lane&15), k = kt*32 + (lane>>4)*8 + j
__global__ void pack_B_kernel(const float* __restrict__ Wc,
                              const float* __restrict__ Wt,
                              unsigned short* __restrict__ Bp) {
    const int frag = blockIdx.x;           // 224 total
    const int kt = frag / NCT, ct = frag % NCT;
    const int lane = threadIdx.x;          // 64
    const int col = ct * 16 + (lane & 15);
    const int k0  = kt * 32 + ((lane >> 4) << 3);
    bf16x8 o;
#pragma unroll
    for (int j = 0; j < 8; ++j) {
        const int k = k0 + j;
        float v = 0.0f;
        if (col < CCLS)      v = Wc[k * CCLS + col];
        else if (col < NCOL) v = Wt[k * CTF + (col - CCLS)];
        o[j] = (short)f2bf_rne(v);
    }
    *reinterpret_cast<bf16x8*>(Bp + ((size_t)frag * 64 + lane) * 8) = o;
}

// Measured-best structure (R4, 153.3 us = 537 MB A-stream / ~3.5 TB/s read
// ceiling): DMA-staged GEMM, per-wave-private LDS slabs via global_load_lds
// (no __syncthreads anywhere), double-buffered, counted vmcnt(8) so the next
// slab's DMA stays in flight. LDS linear dest + pre-swizzled global source
// + XOR-swizzled ds_read (conflict-free at 256B row stride).
__global__ __launch_bounds__(256, 2)
void roi_gemm_kernel(const float* __restrict__ F,
                     const unsigned short* __restrict__ Bp,
                     const float* __restrict__ bcls,
                     const float* __restrict__ btf,
                     float* __restrict__ out) {
    // [buf][wave][row 0..31][chunk16B 0..15] = 64 KiB
    __shared__ float Alds[2][4][32][BKF];

    const int t    = threadIdx.x;
    const int wave = t >> 6;
    const int lane = t & 63;
    const int fr   = lane & 15;      // A/C row-in-tile, B col
    const int fq   = lane >> 4;      // 0..3
    const int sw   = fr & 7;         // read-side XOR swizzle

    const long rw = (long)blockIdx.x * BM + wave * 32;

    // staging sources: DMA instr q writes rows q*4..q*4+3 linearly; lane's
    // row r = q*4+fq, slot fr must hold global chunk fr ^ (r&7).
    // r&7 = fq (q even) or fq+4 (q odd).
    const float* srcE = F + (size_t)(rw + fq) * DK + ((fr ^ fq) << 2);
    const float* srcO = F + (size_t)(rw + fq) * DK + ((fr ^ (fq + 4)) << 2);
    const unsigned short* bb = Bp + (size_t)lane * 8;

    f32x4 acc[2][NCT];
#pragma unroll
    for (int a = 0; a < 2; ++a)
#pragma unroll
        for (int b = 0; b < NCT; ++b)
            acc[a][b] = (f32x4){0.f, 0.f, 0.f, 0.f};

#define STAGE(BUF, S) do {                                                   \
    const float* _e = srcE + (size_t)(S) * BKF;                              \
    const float* _o = srcO + (size_t)(S) * BKF;                              \
    _Pragma("unroll")                                                        \
    for (int q = 0; q < 8; ++q) {                                            \
        const float* g = ((q & 1) ? _o : _e) + (size_t)q * 4 * DK;           \
        __builtin_amdgcn_global_load_lds((GV*)g,                             \
            (LV*)&Alds[BUF][wave][q * 4][0], 16, 0, 0);                      \
    }                                                                        \
} while (0)

    STAGE(0, 0);   // prologue: 8 DMA outstanding

    for (int s = 0; s < NSLAB; ++s) {
        const int buf = s & 1;

        __builtin_amdgcn_sched_barrier(0);
        // B fragments for this slab (L2-resident), 14 loads
        bf16x8 bf[2][NCT];
#pragma unroll
        for (int kt = 0; kt < 2; ++kt)
#pragma unroll
            for (int ct = 0; ct < NCT; ++ct)
                bf[kt][ct] = *reinterpret_cast<const bf16x8*>(
                    bb + ((size_t)((s * 2 + kt) * NCT + ct) * 512));
        __builtin_amdgcn_sched_barrier(0);

        // FIFO: [DMA(s)=8][B(s)=14][DMA(s+1)=8] -> vmcnt(8) completes
        // DMA(s)+B(s) while keeping DMA(s+1) in flight.
        if (s + 1 < NSLAB) {
            STAGE((s + 1) & 1, s + 1);
            __builtin_amdgcn_sched_barrier(0);
            asm volatile("s_waitcnt vmcnt(8)" ::: "memory");
        } else {
            asm volatile("s_waitcnt vmcnt(0)" ::: "memory");
        }
        __builtin_amdgcn_sched_barrier(0);

#pragma unroll
        for (int kt = 0; kt < 2; ++kt) {
            bf16x8 af[2];
#pragma unroll
            for (int rt = 0; rt < 2; ++rt) {
                const float* lpr = &Alds[buf][wave][rt * 16 + fr][0];
                const int c0 = kt * 8 + fq * 2;
                const f32x4 lo = *reinterpret_cast<const f32x4*>(
                    lpr + (((c0 + 0) ^ sw) << 2));
                const f32x4 hi = *reinterpret_cast<const f32x4*>(
                    lpr + (((c0 + 1) ^ sw) << 2));
                af[rt] = cvt8v(lo, hi);
            }
#pragma unroll
            for (int ct = 0; ct < NCT; ++ct) {
                acc[0][ct] = __builtin_amdgcn_mfma_f32_16x16x32_bf16(
                    af[0], bf[kt][ct], acc[0][ct], 0, 0, 0);
                acc[1][ct] = __builtin_amdgcn_mfma_f32_16x16x32_bf16(
                    af[1], bf[kt][ct], acc[1][ct], 0, 0, 0);
            }
        }
    }
#undef STAGE

    // epilogue: bias + scatter into the two outputs (layout verified)
    float* out_tf = out + (size_t)NROWS * CCLS;
#pragma unroll
    for (int rt = 0; rt < 2; ++rt) {
        const long rbase = rw + rt * 16 + (fq << 2);
#pragma unroll
        for (int ct = 0; ct < NCT; ++ct) {
            const int col = ct * 16 + fr;
            if (col >= NCOL) continue;
            const float bias = (col < CCLS) ? bcls[col] : btf[col - CCLS];
#pragma unroll
            for (int j = 0; j < 4; ++j) {
                const long row = rbase + j;
                const float v = acc[rt][ct][j] + bias;
                if (col < CCLS) out[row * CCLS + col] = v;
                else            out_tf[row * CTF + (col - CCLS)] = v;
            }
        }
    }
}

extern "C" void kernel_launch(void* const* d_in, const int* in_sizes, int n_in,
                              void* d_out, int out_size, void* d_ws, size_t ws_size,
                              hipStream_t stream) {
    const float* F  = (const float*)d_in[0];
    const float* Wc = (const float*)d_in[1];
    const float* bc = (const float*)d_in[2];
    const float* Wt = (const float*)d_in[3];
    const float* bt = (const float*)d_in[4];
    unsigned short* Bp = (unsigned short*)d_ws;   // 229,376 B

    pack_B_kernel<<<NCT * (DK / 32), 64, 0, stream>>>(Wc, Wt, Bp);
    roi_gemm_kernel<<<NROWS / BM, 256, 0, stream>>>(F, Bp, bc, bt,
                                                    (float*)d_out);
}